// Round 1
// baseline (543.163 us; speedup 1.0000x reference)
//
#include <hip/hip_runtime.h>
#include <cmath>

typedef unsigned long long u64;
typedef unsigned int u32;
typedef unsigned char u8;

#define SCAN_BLOCK 256
#define SCAN_ELEMS 8
#define SCAN_TILE (SCAN_BLOCK * SCAN_ELEMS)

// counting-sort bins: 512 vertices per bin (V=200000 -> NB=391, LDS arrays 512)
// record packing (mn&511)<<18 | mx requires V <= 2^18.
#define BIN_SHIFT 9
#define BIN_VR 512
#define TETS_PER_BLOCK 2048

__constant__ int d_NUMTRI[16] = {0,1,1,2,1,2,2,1,1,2,2,1,2,1,1,0};
__constant__ int d_TRI[16][6] = {
 {-1,-1,-1,-1,-1,-1},{1,0,2,-1,-1,-1},{4,0,3,-1,-1,-1},{1,4,2,1,3,4},
 {3,1,5,-1,-1,-1},{2,3,0,2,5,3},{1,4,0,1,5,4},{4,2,5,-1,-1,-1},
 {4,5,2,-1,-1,-1},{4,1,0,4,5,1},{3,2,0,3,5,2},{1,3,5,-1,-1,-1},
 {4,1,2,4,3,1},{3,0,4,-1,-1,-1},{2,0,1,-1,-1,-1},{-1,-1,-1,-1,-1,-1}};
__constant__ int d_E0[6] = {0,0,0,1,1,2};
__constant__ int d_E1[6] = {1,2,3,2,3,3};

// ---------------- exclusive scan, templated element type ----------------
// NOTE: tet m1/m2 scan MUST be u64 — running m1 total needs 19 bits packed at
// bit 21 (overflowed u32 in round 3).
template <typename T>
__global__ void scanA_t(const T* in, T* out, int n, T* blockSums) {
    __shared__ T tsum[SCAN_BLOCK];
    int tbase = blockIdx.x * SCAN_TILE + threadIdx.x * SCAN_ELEMS;
    T vals[SCAN_ELEMS];
    T run = 0;
    for (int k = 0; k < SCAN_ELEMS; ++k) {
        int i = tbase + k;
        T v = (i < n) ? in[i] : (T)0;
        vals[k] = run;
        run += v;
    }
    tsum[threadIdx.x] = run;
    __syncthreads();
    for (int off = 1; off < SCAN_BLOCK; off <<= 1) {
        T v = (threadIdx.x >= (unsigned)off) ? tsum[threadIdx.x - off] : (T)0;
        __syncthreads();
        tsum[threadIdx.x] += v;
        __syncthreads();
    }
    T texcl = (threadIdx.x == 0) ? (T)0 : tsum[threadIdx.x - 1];
    for (int k = 0; k < SCAN_ELEMS; ++k) {
        int i = tbase + k;
        if (i < n) out[i] = texcl + vals[k];
    }
    if (threadIdx.x == SCAN_BLOCK - 1) blockSums[blockIdx.x] = tsum[SCAN_BLOCK - 1];
}

template <typename T>
__global__ void scanB_t(T* bs, int nb, T* totalOut) {
    __shared__ T sh[2048];
    for (int i = threadIdx.x; i < 2048; i += 256) sh[i] = (i < nb) ? bs[i] : (T)0;
    __syncthreads();
    for (int off = 1; off < 2048; off <<= 1) {
        T v[8];
        for (int k = 0; k < 8; ++k) {
            int i = threadIdx.x + k * 256;
            v[k] = (i >= off) ? sh[i - off] : (T)0;
        }
        __syncthreads();
        for (int k = 0; k < 8; ++k) sh[threadIdx.x + k * 256] += v[k];
        __syncthreads();
    }
    for (int i = threadIdx.x; i < nb; i += 256) bs[i] = (i == 0) ? (T)0 : sh[i - 1];
    if (threadIdx.x == 0 && totalOut) *totalOut = (nb > 0) ? sh[nb - 1] : (T)0;
}

template <typename T>
__global__ void scanC_t(T* out, int n, const T* bs) {
    int base = blockIdx.x * SCAN_TILE;
    T add = bs[blockIdx.x];
    int end = base + SCAN_TILE; if (end > n) end = n;
    for (int i = base + threadIdx.x; i < end; i += SCAN_BLOCK) out[i] += add;
}

// ---------------- pipeline ----------------
// Pass A: classify tets + per-block LDS histogram of crossing edges over bins.
__global__ __launch_bounds__(256) void k_classify_hist(
    const int* tet, const float* sdf, u8* ti8, u64* tetPack,
    u32* blockHist, int T, int NB, int gB) {
    __shared__ u32 hist[BIN_VR];
    for (int i = threadIdx.x; i < NB; i += 256) hist[i] = 0;
    __syncthreads();
    int base = blockIdx.x * TETS_PER_BLOCK;
    for (int it = 0; it < TETS_PER_BLOCK / 256; ++it) {
        int t = base + it * 256 + threadIdx.x;
        if (t < T) {
            int4 q = reinterpret_cast<const int4*>(tet)[t];
            int ti = (sdf[q.x] > 0.0f ? 1 : 0) | (sdf[q.y] > 0.0f ? 2 : 0) |
                     (sdf[q.z] > 0.0f ? 4 : 0) | (sdf[q.w] > 0.0f ? 8 : 0);
            ti8[t] = (u8)ti;
            int nt = d_NUMTRI[ti];
            tetPack[t] = ((u64)(nt == 1 ? 1 : 0) << 21) | (u64)(nt == 2 ? 1 : 0);
            if (nt != 0) {
                int idx[4] = {q.x, q.y, q.z, q.w};
                #pragma unroll
                for (int e = 0; e < 6; ++e) {
                    int e0 = d_E0[e], e1 = d_E1[e];
                    if (((ti >> e0) ^ (ti >> e1)) & 1) {
                        int a = idx[e0], b = idx[e1];
                        int mn = a < b ? a : b;
                        atomicAdd(&hist[mn >> BIN_SHIFT], 1u);
                    }
                }
            }
        }
    }
    __syncthreads();
    for (int i = threadIdx.x; i < NB; i += 256)
        blockHist[(size_t)i * gB + blockIdx.x] = hist[i];
}

// Pass B: block-local LDS cursors hand out exact contiguous slots in the
// bin-sorted record array. Writes are block-local bursts.
// NEW: each record also carries its provenance prov = 6*t + e so the
// sort/dedup stage can scatter final edge->vertex ids directly into idx_map
// (kills the per-edge bucket re-scan that dominated k_faces).
__global__ __launch_bounds__(256) void k_binfill(
    const int* tet, const u8* ti8, const u32* blockHistScan,
    u32* binData, u32* binProv, int T, int NB, int gB) {
    __shared__ u32 cur[BIN_VR];
    for (int i = threadIdx.x; i < NB; i += 256)
        cur[i] = blockHistScan[(size_t)i * gB + blockIdx.x];
    __syncthreads();
    int base = blockIdx.x * TETS_PER_BLOCK;
    for (int it = 0; it < TETS_PER_BLOCK / 256; ++it) {
        int t = base + it * 256 + threadIdx.x;
        if (t < T) {
            int ti = ti8[t];
            if (d_NUMTRI[ti] != 0) {
                int4 q = reinterpret_cast<const int4*>(tet)[t];
                int idx[4] = {q.x, q.y, q.z, q.w};
                #pragma unroll
                for (int e = 0; e < 6; ++e) {
                    int e0 = d_E0[e], e1 = d_E1[e];
                    if (((ti >> e0) ^ (ti >> e1)) & 1) {
                        int a = idx[e0], b = idx[e1];
                        int mn = a < b ? a : b;
                        int mx = a < b ? b : a;
                        u32 slot = atomicAdd(&cur[mn >> BIN_SHIFT], 1u);
                        binData[slot] = ((u32)(mn & (BIN_VR - 1)) << 18) | (u32)mx;
                        binProv[slot] = 6u * (u32)t + (u32)e;
                    }
                }
            }
        }
    }
}

// one block per bin: LDS histogram over the bin's record range -> coalesced
// bucketCnt AND 16-rounded padCnt writes (pad kernel fused away)
__global__ __launch_bounds__(256) void k_bincount(
    const u32* blockHistScan, const u32* totalPtr, const u32* binData,
    u32* bucketCnt, u32* padCnt, int V, int NB, int gB) {
    int bin = blockIdx.x;
    __shared__ u32 hist[BIN_VR];
    for (int i = threadIdx.x; i < BIN_VR; i += 256) hist[i] = 0;
    __syncthreads();
    u32 s = blockHistScan[(size_t)bin * gB];
    u32 e = (bin + 1 < NB) ? blockHistScan[(size_t)(bin + 1) * gB] : *totalPtr;
    for (u32 i = s + threadIdx.x; i < e; i += 256)
        atomicAdd(&hist[binData[i] >> 18], 1u);
    __syncthreads();
    int vbase = bin << BIN_SHIFT;
    for (int i = threadIdx.x; i < BIN_VR; i += 256) {
        int v = vbase + i;
        if (v < V) {
            u32 h = hist[i];
            bucketCnt[v] = h;
            padCnt[v] = (h + 15u) & ~15u;
        }
    }
}

// one block per bin: LDS cursors (absolute bucketStart) -> scatter mx into
// maxArr and prov into provArr (same slot). All writes land in the bin's
// contiguous window -> L2-combined.
__global__ __launch_bounds__(256) void k_binscatter(
    const u32* blockHistScan, const u32* totalPtr, const u32* binData,
    const u32* binProv, const u32* bucketStart, u32* maxArr, u32* provArr,
    int V, int NB, int gB) {
    int bin = blockIdx.x;
    __shared__ u32 cur[BIN_VR];
    int vbase = bin << BIN_SHIFT;
    for (int i = threadIdx.x; i < BIN_VR; i += 256) {
        int v = vbase + i;
        cur[i] = (v < V) ? bucketStart[v] : 0u;
    }
    __syncthreads();
    u32 s = blockHistScan[(size_t)bin * gB];
    u32 e = (bin + 1 < NB) ? blockHistScan[(size_t)(bin + 1) * gB] : *totalPtr;
    for (u32 i = s + threadIdx.x; i < e; i += 256) {
        u32 rec = binData[i];
        u32 pv = binProv[i];
        u32 slot = atomicAdd(&cur[rec >> 18], 1u);
        maxArr[slot] = rec & 0x3FFFFu;
        provArr[slot] = pv;
    }
}

// one wave per bucket. Sort + dedup, and scatter each original record's
// final LOCAL dedup index into idx_map[prov] (nontemporal 4B scatter).
// k_faces later adds crossScan[a] to form the global vertex id.
__global__ __launch_bounds__(64) void k_sortdedup(
    const u32* bucketCnt, const u32* bucketStart, u32* maxArr,
    u32* provArr, u32* idxmap, u32* crossCnt, int V)
{
    int v = blockIdx.x;
    if (v >= V) return;
    int lane = threadIdx.x;
    int n = (int)bucketCnt[v];
    if (n == 0) { if (lane == 0) crossCnt[v] = 0; return; }
    long long start = (long long)bucketStart[v];

    if (n <= 64) {
        u32 key = (lane < n) ? maxArr[start + lane] : 0xFFFFFFFFu;
        u32 prov = (lane < n) ? provArr[start + lane] : 0u;
        int rank = 0;
        for (int j = 0; j < n; ++j) {           // dynamic bound: avg n~15
            u32 kj = (u32)__shfl((int)key, j);
            rank += (kj < key || (kj == key && j < lane)) ? 1 : 0;
        }
        u32 sorted = (u32)__builtin_amdgcn_ds_permute(rank << 2, (int)key);
        u32 prev = (u32)__shfl((int)sorted, lane - 1);
        bool nf = (lane < n) && (lane == 0 || prev != sorted);
        u64 m = __ballot(nf);
        int idx = __popcll(m & ((1ull << lane) - 1ull));
        if (nf) maxArr[start + idx] = sorted;
        int ldSorted = nf ? idx : idx - 1;      // dedup idx at sorted pos `lane`
        int ldOrig = __shfl(ldSorted, rank);    // my record sits at pos `rank`
        if (lane < n)
            __builtin_nontemporal_store((u32)ldOrig, &idxmap[prov]);
        if (lane == 0) crossCnt[v] = (u32)__popcll(m);
    } else if (n <= 1024) {
        __shared__ u32 sk[1024];
        __shared__ u32 ss[1024];
        __shared__ u32 sdd[1024];
        int chunks = (n + 63) >> 6;             // <= 16
        u32 key[16];
        int rank[16];
        #pragma unroll
        for (int c = 0; c < 16; ++c) {
            if (c < chunks) {
                int i = (c << 6) + lane;
                key[c] = (i < n) ? maxArr[start + i] : 0xFFFFFFFFu;
                sk[(c << 6) + lane] = key[c];
                rank[c] = 0;
            }
        }
        __syncthreads();
        for (int j = 0; j < n; ++j) {
            u32 kj = sk[j];
            #pragma unroll
            for (int c = 0; c < 16; ++c) {
                if (c < chunks) {
                    int i = (c << 6) + lane;
                    rank[c] += (kj < key[c] || (kj == key[c] && j < i)) ? 1 : 0;
                }
            }
        }
        #pragma unroll
        for (int c = 0; c < 16; ++c) {
            if (c < chunks) { int i = (c << 6) + lane; if (i < n) ss[rank[c]] = key[c]; }
        }
        __syncthreads();
        int carryU = 0;
        for (int c = 0; c < chunks; ++c) {
            int i = (c << 6) + lane;
            bool valid = i < n;
            u32 k = ss[valid ? i : n - 1];
            bool nf = valid && (i == 0 || ss[i - 1] != k);
            u64 mnf = __ballot(nf);
            u64 incl = (2ull << lane) - 1ull;
            int uIncl = carryU + __popcll(mnf & incl);
            if (nf) maxArr[start + uIncl - 1] = k;
            if (valid) sdd[i] = (u32)(uIncl - 1);
            carryU += __popcll(mnf);
        }
        __syncthreads();
        #pragma unroll
        for (int c = 0; c < 16; ++c) {
            if (c < chunks) {
                int i = (c << 6) + lane;
                if (i < n)
                    __builtin_nontemporal_store(sdd[rank[c]],
                                                &idxmap[provArr[start + i]]);
            }
        }
        if (lane == 0) crossCnt[v] = (u32)carryU;
    } else if (lane == 0) {
        // cold path: insertion-sort (key,prov) pairs together, then dedup.
        for (int i = 1; i < n; ++i) {
            u32 kk = maxArr[start + i];
            u32 pp = provArr[start + i];
            int j = i - 1;
            while (j >= 0 && maxArr[start + j] > kk) {
                maxArr[start + j + 1] = maxArr[start + j];
                provArr[start + j + 1] = provArr[start + j];
                --j;
            }
            maxArr[start + j + 1] = kk;
            provArr[start + j + 1] = pp;
        }
        int uc = 0; u32 prev = 0xFFFFFFFFu;
        for (int i = 0; i < n; ++i) {
            u32 k = maxArr[start + i];
            if (k != prev) { maxArr[start + uc] = k; ++uc; prev = k; }
            __builtin_nontemporal_store((u32)(uc - 1),
                                        &idxmap[provArr[start + i]]);
        }
        crossCnt[v] = (u32)uc;
    }
}

// one wave per bucket; lane i -> unique crossing edge i -> vertex crossScan[v]+i
__global__ __launch_bounds__(64) void k_verts(
    const u32* crossCnt, const u32* bucketStart, const u32* maxArr, const u32* crossScan,
    const float* pos, const float* sdf, float* out, int V)
{
    int v = blockIdx.x;
    if (v >= V) return;
    int lane = threadIdx.x;
    int u = (int)crossCnt[v];
    if (u == 0) return;
    long long start = (long long)bucketStart[v];
    int cBase = (int)crossScan[v];
    float s0 = sdf[v];
    float p0x = pos[3 * v], p0y = pos[3 * v + 1], p0z = pos[3 * v + 2];
    for (int i = lane; i < u; i += 64) {
        int b = (int)maxArr[start + i];
        long long k = cBase + i;
        float s1 = sdf[b];
        float d = s0 - s1;
        float w0 = -s1 / d, w1 = s0 / d;
        out[3 * k + 0] = p0x * w0 + pos[3 * b + 0] * w1;
        out[3 * k + 1] = p0y * w0 + pos[3 * b + 1] * w1;
        out[3 * k + 2] = p0z * w0 + pos[3 * b + 2] * w1;
    }
}

// faces + uv_idx. Edge->vertex id is now a direct read: idx_map[6t+e] holds
// the local dedup index within bucket(a); global id = crossScan[a] + local.
// Pure streaming kernel (was: latency-bound per-edge bucket re-scan).
__global__ void k_faces(const int* tet, const u8* ti8, const u64* tetScan,
                        const u32* idxmap, const u32* crossScan,
                        const u64* meta0, const u32* NePtr,
                        float* out, int T, int Ngrid, long long uvFloats)
{
    int t = blockIdx.x * 256 + threadIdx.x;
    if (t >= T) return;
    int ti = ti8[t];
    int nt = d_NUMTRI[ti];
    if (nt == 0) return;

    u64 tot = *meta0;
    int C1 = (int)((tot >> 21) & 0x1fffffull);
    int C2 = (int)(tot & 0x1fffffull);
    int Ne = (int)*NePtr;
    long long facesBase = 3LL * Ne;
    long long F = (long long)C1 + 2LL * C2;
    long long uvIdxBase = facesBase + 3LL * F + uvFloats;

    int4 q = reinterpret_cast<const int4*>(tet)[t];
    int idx[4] = {q.x, q.y, q.z, q.w};
    const uint2* imp = reinterpret_cast<const uint2*>(idxmap + 6ll * t);
    uint2 r0 = imp[0], r1 = imp[1], r2 = imp[2];
    u32 im[6] = {r0.x, r0.y, r1.x, r1.y, r2.x, r2.y};
    const int* row = d_TRI[ti];

    int emap[6];
    unsigned done = 0;
    float fv[6];
    #pragma unroll
    for (int j = 0; j < 6; ++j) {
        if (j >= 3 * nt) break;
        int e = row[j];
        if (!((done >> e) & 1)) {
            done |= 1u << e;
            int a = idx[d_E0[e]], b = idx[d_E1[e]];
            if (b < a) a = b;                  // a = min endpoint = bucket
            emap[e] = (int)crossScan[a] + (int)im[e];
        }
        fv[j] = (float)emap[e];
    }

    u64 sc = tetScan[t];
    int r1s = (int)((sc >> 21) & 0x1fffffull);
    int r2s = (int)(sc & 0x1fffffull);
    int tet_idx = (t / Ngrid) * Ngrid + (t % Ngrid);

    if (nt == 1) {
        long long f = r1s;
        out[facesBase + 3 * f + 0] = fv[0];
        out[facesBase + 3 * f + 1] = fv[1];
        out[facesBase + 3 * f + 2] = fv[2];
        out[uvIdxBase + 3 * f + 0] = (float)(4 * tet_idx);
        out[uvIdxBase + 3 * f + 1] = (float)(4 * tet_idx + 1);
        out[uvIdxBase + 3 * f + 2] = (float)(4 * tet_idx + 2);
    } else {
        long long f0 = (long long)C1 + 2LL * r2s;
        out[facesBase + 3 * f0 + 0] = fv[0];
        out[facesBase + 3 * f0 + 1] = fv[1];
        out[facesBase + 3 * f0 + 2] = fv[2];
        out[facesBase + 3 * (f0 + 1) + 0] = fv[3];
        out[facesBase + 3 * (f0 + 1) + 1] = fv[4];
        out[facesBase + 3 * (f0 + 1) + 2] = fv[5];
        out[uvIdxBase + 3 * f0 + 0] = (float)(4 * tet_idx);
        out[uvIdxBase + 3 * f0 + 1] = (float)(4 * tet_idx + 1);
        out[uvIdxBase + 3 * f0 + 2] = (float)(4 * tet_idx + 2);
        out[uvIdxBase + 3 * (f0 + 1) + 0] = (float)(4 * tet_idx);
        out[uvIdxBase + 3 * (f0 + 1) + 1] = (float)(4 * tet_idx + 2);
        out[uvIdxBase + 3 * (f0 + 1) + 2] = (float)(4 * tet_idx + 3);
    }
}

__global__ void k_uvs(float* out, const u64* meta0, const u32* NePtr, int Ngrid) {
    int c = blockIdx.x * 256 + threadIdx.x;
    int total = Ngrid * Ngrid;
    if (c >= total) return;
    u64 tot = *meta0;
    int C1 = (int)((tot >> 21) & 0x1fffffull);
    int C2 = (int)(tot & 0x1fffffull);
    int Ne = (int)*NePtr;
    long long uvBase = 3LL * Ne + 3LL * ((long long)C1 + 2LL * C2);
    int i = c / Ngrid, j = c % Ngrid;
    double step = (Ngrid > 1) ? (1.0 - 1.0 / (double)Ngrid) / (double)(Ngrid - 1) : 0.0;
    float x = (float)((double)j * step);
    float y = (float)((double)i * step);
    float pad = (float)(0.9 / (double)Ngrid);
    long long o = uvBase + 8LL * c;
    out[o + 0] = x;       out[o + 1] = y;
    out[o + 2] = x + pad; out[o + 3] = y;
    out[o + 4] = x + pad; out[o + 5] = y + pad;
    out[o + 6] = x;       out[o + 7] = y + pad;
}

// ---------------- host ----------------
template <typename T>
static void run_scan_t(const T* in, T* out, int n, T* blockSums, T* totalOut,
                       hipStream_t stream) {
    int nb = (n + SCAN_TILE - 1) / SCAN_TILE;
    scanA_t<T><<<nb, SCAN_BLOCK, 0, stream>>>(in, out, n, blockSums);
    scanB_t<T><<<1, 256, 0, stream>>>(blockSums, nb, totalOut);
    scanC_t<T><<<nb, SCAN_BLOCK, 0, stream>>>(out, n, blockSums);
}

extern "C" void kernel_launch(void* const* d_in, const int* in_sizes, int n_in,
                              void* d_out, int out_size, void* d_ws, size_t ws_size,
                              hipStream_t stream) {
    const float* pos = (const float*)d_in[0];
    const float* sdf = (const float*)d_in[1];
    const int* tet = (const int*)d_in[2];
    int V = in_sizes[1];
    int T = in_sizes[2] / 4;
    float* out = (float*)d_out;

    int NB = (V + BIN_VR - 1) / BIN_VR;
    int gB = (T + TETS_PER_BLOCK - 1) / TETS_PER_BLOCK;
    int nHist = NB * gB;

    char* p = (char*)d_ws;
    auto alloc = [&](size_t bytes) -> void* {
        void* r = (void*)p;
        p += (bytes + 255) & ~(size_t)255;
        return r;
    };
    u8*  ti8           = (u8*) alloc((size_t)T);
    u64* tetPack       = (u64*)alloc((size_t)T * 8);
    u64* tetScan       = (u64*)alloc((size_t)T * 8);
    u32* blockHist     = (u32*)alloc((size_t)nHist * 4);
    u32* blockHistScan = (u32*)alloc((size_t)nHist * 4);
    u32* binData       = (u32*)alloc((size_t)6 * T * 4);   // reused as idxmap
    u32* binProv       = (u32*)alloc((size_t)6 * T * 4);
    u32* bucketCnt     = (u32*)alloc((size_t)V * 4);
    u32* padCnt        = (u32*)alloc((size_t)V * 4);
    u32* bucketStart   = (u32*)alloc((size_t)V * 4);
    u32* crossCnt      = (u32*)alloc((size_t)V * 4);
    u32* crossScan     = (u32*)alloc((size_t)V * 4);
    u32* maxArr        = (u32*)alloc(((size_t)6 * T + 16 * (size_t)V) * 4);
    u32* provArr       = (u32*)alloc(((size_t)6 * T + 16 * (size_t)V) * 4);
    u64* blockSums64   = (u64*)alloc(2048 * 8);
    u32* blockSums32   = (u32*)alloc(2048 * 4);
    u64* meta64        = (u64*)alloc(8 * 8);
    u32* NePtr         = (u32*)(meta64 + 4);
    u32* NeInstPtr     = (u32*)(meta64 + 5);

    // idx_map[t*6+e] aliases binData: binData's last reader is k_binscatter,
    // idxmap's first writer is k_sortdedup (strictly after). 6T u32 exactly.
    u32* idxmap = binData;

    long long M = (2LL * T + 1) / 2;
    int Ngrid = (int)std::sqrt((double)M);
    while ((long long)Ngrid * Ngrid < M) ++Ngrid;
    if (Ngrid < 1) Ngrid = 1;
    long long uvFloats = 8LL * Ngrid * Ngrid;

    int gT = (T + 255) / 256;

    k_classify_hist<<<gB, 256, 0, stream>>>(tet, sdf, ti8, tetPack, blockHist,
                                            T, NB, gB);
    run_scan_t<u64>(tetPack, tetScan, T, blockSums64, meta64, stream);
    run_scan_t<u32>(blockHist, blockHistScan, nHist, blockSums32, NeInstPtr, stream);
    k_binfill<<<gB, 256, 0, stream>>>(tet, ti8, blockHistScan, binData, binProv,
                                      T, NB, gB);
    k_bincount<<<NB, 256, 0, stream>>>(blockHistScan, NeInstPtr, binData,
                                       bucketCnt, padCnt, V, NB, gB);
    run_scan_t<u32>(padCnt, bucketStart, V, blockSums32, nullptr, stream);
    k_binscatter<<<NB, 256, 0, stream>>>(blockHistScan, NeInstPtr, binData,
                                         binProv, bucketStart, maxArr, provArr,
                                         V, NB, gB);
    k_sortdedup<<<V, 64, 0, stream>>>(bucketCnt, bucketStart, maxArr,
                                      provArr, idxmap, crossCnt, V);
    run_scan_t<u32>(crossCnt, crossScan, V, blockSums32, NePtr, stream);
    k_verts<<<V, 64, 0, stream>>>(crossCnt, bucketStart, maxArr, crossScan,
                                  pos, sdf, out, V);
    k_faces<<<gT, 256, 0, stream>>>(tet, ti8, tetScan, idxmap, crossScan,
                                    meta64, NePtr, out, T, Ngrid, uvFloats);
    int gUV = (Ngrid * Ngrid + 255) / 256;
    k_uvs<<<gUV, 256, 0, stream>>>(out, meta64, NePtr, Ngrid);
}

// Round 2
// 501.477 us; speedup vs baseline: 1.0831x; 1.0831x over previous
//
#include <hip/hip_runtime.h>
#include <cmath>

typedef unsigned long long u64;
typedef unsigned int u32;
typedef unsigned char u8;

#define SCAN_BLOCK 256
#define SCAN_ELEMS 8
#define SCAN_TILE (SCAN_BLOCK * SCAN_ELEMS)

// counting-sort bins: 512 vertices per bin (V=200000 -> NB=391, LDS arrays 512)
// record packing (mn&511)<<18 | mx requires V <= 2^18.
#define BIN_SHIFT 9
#define BIN_VR 512
#define TETS_PER_BLOCK 2048

__constant__ int d_NUMTRI[16] = {0,1,1,2,1,2,2,1,1,2,2,1,2,1,1,0};
__constant__ int d_TRI[16][6] = {
 {-1,-1,-1,-1,-1,-1},{1,0,2,-1,-1,-1},{4,0,3,-1,-1,-1},{1,4,2,1,3,4},
 {3,1,5,-1,-1,-1},{2,3,0,2,5,3},{1,4,0,1,5,4},{4,2,5,-1,-1,-1},
 {4,5,2,-1,-1,-1},{4,1,0,4,5,1},{3,2,0,3,5,2},{1,3,5,-1,-1,-1},
 {4,1,2,4,3,1},{3,0,4,-1,-1,-1},{2,0,1,-1,-1,-1},{-1,-1,-1,-1,-1,-1}};
__constant__ int d_E0[6] = {0,0,0,1,1,2};
__constant__ int d_E1[6] = {1,2,3,2,3,3};

// ---------------- exclusive scan, templated element type ----------------
// NOTE: tet m1/m2 scan MUST be u64 — running m1 total needs 19 bits packed at
// bit 21 (overflowed u32 in round 3).
template <typename T>
__global__ void scanA_t(const T* in, T* out, int n, T* blockSums) {
    __shared__ T tsum[SCAN_BLOCK];
    int tbase = blockIdx.x * SCAN_TILE + threadIdx.x * SCAN_ELEMS;
    T vals[SCAN_ELEMS];
    T run = 0;
    for (int k = 0; k < SCAN_ELEMS; ++k) {
        int i = tbase + k;
        T v = (i < n) ? in[i] : (T)0;
        vals[k] = run;
        run += v;
    }
    tsum[threadIdx.x] = run;
    __syncthreads();
    for (int off = 1; off < SCAN_BLOCK; off <<= 1) {
        T v = (threadIdx.x >= (unsigned)off) ? tsum[threadIdx.x - off] : (T)0;
        __syncthreads();
        tsum[threadIdx.x] += v;
        __syncthreads();
    }
    T texcl = (threadIdx.x == 0) ? (T)0 : tsum[threadIdx.x - 1];
    for (int k = 0; k < SCAN_ELEMS; ++k) {
        int i = tbase + k;
        if (i < n) out[i] = texcl + vals[k];
    }
    if (threadIdx.x == SCAN_BLOCK - 1) blockSums[blockIdx.x] = tsum[SCAN_BLOCK - 1];
}

template <typename T>
__global__ void scanB_t(T* bs, int nb, T* totalOut) {
    __shared__ T sh[2048];
    for (int i = threadIdx.x; i < 2048; i += 256) sh[i] = (i < nb) ? bs[i] : (T)0;
    __syncthreads();
    for (int off = 1; off < 2048; off <<= 1) {
        T v[8];
        for (int k = 0; k < 8; ++k) {
            int i = threadIdx.x + k * 256;
            v[k] = (i >= off) ? sh[i - off] : (T)0;
        }
        __syncthreads();
        for (int k = 0; k < 8; ++k) sh[threadIdx.x + k * 256] += v[k];
        __syncthreads();
    }
    for (int i = threadIdx.x; i < nb; i += 256) bs[i] = (i == 0) ? (T)0 : sh[i - 1];
    if (threadIdx.x == 0 && totalOut) *totalOut = (nb > 0) ? sh[nb - 1] : (T)0;
}

template <typename T>
__global__ void scanC_t(T* out, int n, const T* bs) {
    int base = blockIdx.x * SCAN_TILE;
    T add = bs[blockIdx.x];
    int end = base + SCAN_TILE; if (end > n) end = n;
    for (int i = base + threadIdx.x; i < end; i += SCAN_BLOCK) out[i] += add;
}

// ---------------- pipeline ----------------
// Pass A: classify tets + per-block LDS histogram of crossing edges over bins.
// Also zeroes the big-bucket overflow counter (graph-replay safe).
__global__ __launch_bounds__(256) void k_classify_hist(
    const int* tet, const float* sdf, u8* ti8, u64* tetPack,
    u32* blockHist, u32* bigCnt, int T, int NB, int gB) {
    if (blockIdx.x == 0 && threadIdx.x == 0) *bigCnt = 0;
    __shared__ u32 hist[BIN_VR];
    for (int i = threadIdx.x; i < NB; i += 256) hist[i] = 0;
    __syncthreads();
    int base = blockIdx.x * TETS_PER_BLOCK;
    for (int it = 0; it < TETS_PER_BLOCK / 256; ++it) {
        int t = base + it * 256 + threadIdx.x;
        if (t < T) {
            int4 q = reinterpret_cast<const int4*>(tet)[t];
            int ti = (sdf[q.x] > 0.0f ? 1 : 0) | (sdf[q.y] > 0.0f ? 2 : 0) |
                     (sdf[q.z] > 0.0f ? 4 : 0) | (sdf[q.w] > 0.0f ? 8 : 0);
            ti8[t] = (u8)ti;
            int nt = d_NUMTRI[ti];
            tetPack[t] = ((u64)(nt == 1 ? 1 : 0) << 21) | (u64)(nt == 2 ? 1 : 0);
            if (nt != 0) {
                int idx[4] = {q.x, q.y, q.z, q.w};
                #pragma unroll
                for (int e = 0; e < 6; ++e) {
                    int e0 = d_E0[e], e1 = d_E1[e];
                    if (((ti >> e0) ^ (ti >> e1)) & 1) {
                        int a = idx[e0], b = idx[e1];
                        int mn = a < b ? a : b;
                        atomicAdd(&hist[mn >> BIN_SHIFT], 1u);
                    }
                }
            }
        }
    }
    __syncthreads();
    for (int i = threadIdx.x; i < NB; i += 256)
        blockHist[(size_t)i * gB + blockIdx.x] = hist[i];
}

// Pass B: block-local LDS cursors hand out exact contiguous slots in the
// bin-sorted record array. Records carry provenance prov = 6*t + e so the
// sort/dedup stage can scatter final edge->vertex ids directly into idx_map.
__global__ __launch_bounds__(256) void k_binfill(
    const int* tet, const u8* ti8, const u32* blockHistScan,
    u32* binData, u32* binProv, int T, int NB, int gB) {
    __shared__ u32 cur[BIN_VR];
    for (int i = threadIdx.x; i < NB; i += 256)
        cur[i] = blockHistScan[(size_t)i * gB + blockIdx.x];
    __syncthreads();
    int base = blockIdx.x * TETS_PER_BLOCK;
    for (int it = 0; it < TETS_PER_BLOCK / 256; ++it) {
        int t = base + it * 256 + threadIdx.x;
        if (t < T) {
            int ti = ti8[t];
            if (d_NUMTRI[ti] != 0) {
                int4 q = reinterpret_cast<const int4*>(tet)[t];
                int idx[4] = {q.x, q.y, q.z, q.w};
                #pragma unroll
                for (int e = 0; e < 6; ++e) {
                    int e0 = d_E0[e], e1 = d_E1[e];
                    if (((ti >> e0) ^ (ti >> e1)) & 1) {
                        int a = idx[e0], b = idx[e1];
                        int mn = a < b ? a : b;
                        int mx = a < b ? b : a;
                        u32 slot = atomicAdd(&cur[mn >> BIN_SHIFT], 1u);
                        binData[slot] = ((u32)(mn & (BIN_VR - 1)) << 18) | (u32)mx;
                        binProv[slot] = 6u * (u32)t + (u32)e;
                    }
                }
            }
        }
    }
}

// one block per bin: LDS histogram over the bin's record range -> coalesced
// bucketCnt AND 4-rounded padCnt writes
__global__ __launch_bounds__(256) void k_bincount(
    const u32* blockHistScan, const u32* totalPtr, const u32* binData,
    u32* bucketCnt, u32* padCnt, int V, int NB, int gB) {
    int bin = blockIdx.x;
    __shared__ u32 hist[BIN_VR];
    for (int i = threadIdx.x; i < BIN_VR; i += 256) hist[i] = 0;
    __syncthreads();
    u32 s = blockHistScan[(size_t)bin * gB];
    u32 e = (bin + 1 < NB) ? blockHistScan[(size_t)(bin + 1) * gB] : *totalPtr;
    for (u32 i = s + threadIdx.x; i < e; i += 256)
        atomicAdd(&hist[binData[i] >> 18], 1u);
    __syncthreads();
    int vbase = bin << BIN_SHIFT;
    for (int i = threadIdx.x; i < BIN_VR; i += 256) {
        int v = vbase + i;
        if (v < V) {
            u32 h = hist[i];
            bucketCnt[v] = h;
            padCnt[v] = (h + 3u) & ~3u;
        }
    }
}

// one block per bin: LDS cursors (absolute bucketStart) -> scatter fused
// (mx, prov) uint2 records. All writes land in the bin's contiguous window.
__global__ __launch_bounds__(256) void k_binscatter(
    const u32* blockHistScan, const u32* totalPtr, const u32* binData,
    const u32* binProv, const u32* bucketStart, uint2* rec2,
    int V, int NB, int gB) {
    int bin = blockIdx.x;
    __shared__ u32 cur[BIN_VR];
    int vbase = bin << BIN_SHIFT;
    for (int i = threadIdx.x; i < BIN_VR; i += 256) {
        int v = vbase + i;
        cur[i] = (v < V) ? bucketStart[v] : 0u;
    }
    __syncthreads();
    u32 s = blockHistScan[(size_t)bin * gB];
    u32 e = (bin + 1 < NB) ? blockHistScan[(size_t)(bin + 1) * gB] : *totalPtr;
    for (u32 i = s + threadIdx.x; i < e; i += 256) {
        u32 rec = binData[i];
        u32 pv = binProv[i];
        u32 slot = atomicAdd(&cur[rec >> 18], 1u);
        rec2[slot] = make_uint2(rec & 0x3FFFFu, pv);
    }
}

// HOT sort+dedup: 4 buckets per 256-thread block (one per wave), ZERO LDS,
// no barriers -> wave-count-limited occupancy. Handles n<=64 (P(n>64)~0 for
// Poisson(15) bucket sizes); larger buckets deferred to k_sortbig via list.
// Scatters each record's LOCAL dedup index into idx_map[prov] (nontemporal).
__global__ __launch_bounds__(256) void k_sortdedup(
    const u32* bucketCnt, const u32* bucketStart, uint2* rec2,
    u32* idxmap, u32* crossCnt, u32* bigList, u32* bigCnt, int V)
{
    int v = blockIdx.x * 4 + (threadIdx.x >> 6);
    if (v >= V) return;
    int lane = threadIdx.x & 63;
    int n = (int)bucketCnt[v];
    if (n == 0) { if (lane == 0) crossCnt[v] = 0; return; }
    if (n > 64) {
        if (lane == 0) bigList[atomicAdd(bigCnt, 1u)] = (u32)v;
        return;
    }
    long long start = (long long)bucketStart[v];
    uint2 rp = (lane < n) ? rec2[start + lane] : make_uint2(0xFFFFFFFFu, 0u);
    u32 key = rp.x, prov = rp.y;
    int rank = 0;
    for (int j = 0; j < n; ++j) {               // dynamic bound: avg n~15
        u32 kj = (u32)__shfl((int)key, j);
        rank += (kj < key || (kj == key && j < lane)) ? 1 : 0;
    }
    u32 sorted = (u32)__builtin_amdgcn_ds_permute(rank << 2, (int)key);
    u32 prev = (u32)__shfl((int)sorted, lane - 1);
    bool nf = (lane < n) && (lane == 0 || prev != sorted);
    u64 m = __ballot(nf);
    int idx = __popcll(m & ((1ull << lane) - 1ull));
    if (nf) rec2[start + idx].x = sorted;
    int ldSorted = nf ? idx : idx - 1;          // dedup idx at sorted pos `lane`
    int ldOrig = __shfl(ldSorted, rank);        // my record sits at pos `rank`
    if (lane < n)
        __builtin_nontemporal_store((u32)ldOrig, &idxmap[prov]);
    if (lane == 0) crossCnt[v] = (u32)__popcll(m);
}

// COLD big-bucket path: grid-stride over the overflow list. One wave per
// block; LDS rank-sort for n<=1024, serial pair insertion sort beyond.
// Runs ~never for this data; occupancy irrelevant.
__global__ __launch_bounds__(64) void k_sortbig(
    const u32* bigList, const u32* bigCnt, const u32* bucketCnt,
    const u32* bucketStart, uint2* rec2, u32* idxmap, u32* crossCnt)
{
    int nbig = (int)*bigCnt;
    int lane = threadIdx.x;
    __shared__ u32 sk[1024];
    __shared__ u32 ss[1024];
    __shared__ u32 sdd[1024];
    for (int b = blockIdx.x; b < nbig; b += gridDim.x) {
        int v = (int)bigList[b];
        int n = (int)bucketCnt[v];
        long long start = (long long)bucketStart[v];
        if (n <= 1024) {
            int chunks = (n + 63) >> 6;         // <= 16
            u32 key[16];
            int rank[16];
            #pragma unroll
            for (int c = 0; c < 16; ++c) {
                if (c < chunks) {
                    int i = (c << 6) + lane;
                    key[c] = (i < n) ? rec2[start + i].x : 0xFFFFFFFFu;
                    sk[(c << 6) + lane] = key[c];
                    rank[c] = 0;
                }
            }
            __syncthreads();
            for (int j = 0; j < n; ++j) {
                u32 kj = sk[j];
                #pragma unroll
                for (int c = 0; c < 16; ++c) {
                    if (c < chunks) {
                        int i = (c << 6) + lane;
                        rank[c] += (kj < key[c] || (kj == key[c] && j < i)) ? 1 : 0;
                    }
                }
            }
            #pragma unroll
            for (int c = 0; c < 16; ++c) {
                if (c < chunks) { int i = (c << 6) + lane; if (i < n) ss[rank[c]] = key[c]; }
            }
            __syncthreads();
            int carryU = 0;
            for (int c = 0; c < chunks; ++c) {
                int i = (c << 6) + lane;
                bool valid = i < n;
                u32 k = ss[valid ? i : n - 1];
                bool nf = valid && (i == 0 || ss[i - 1] != k);
                u64 mnf = __ballot(nf);
                u64 incl = (2ull << lane) - 1ull;
                int uIncl = carryU + __popcll(mnf & incl);
                if (nf) rec2[start + uIncl - 1].x = k;
                if (valid) sdd[i] = (u32)(uIncl - 1);
                carryU += __popcll(mnf);
            }
            __syncthreads();
            #pragma unroll
            for (int c = 0; c < 16; ++c) {
                if (c < chunks) {
                    int i = (c << 6) + lane;
                    if (i < n)
                        __builtin_nontemporal_store(sdd[rank[c]],
                                                    &idxmap[rec2[start + i].y]);
                }
            }
            if (lane == 0) crossCnt[v] = (u32)carryU;
            __syncthreads();                    // LDS reuse across list items
        } else if (lane == 0) {
            // serial: insertion-sort (key,prov) pairs, then dedup.
            for (int i = 1; i < n; ++i) {
                uint2 kk = rec2[start + i];
                int j = i - 1;
                while (j >= 0 && rec2[start + j].x > kk.x) {
                    rec2[start + j + 1] = rec2[start + j]; --j;
                }
                rec2[start + j + 1] = kk;
            }
            int uc = 0; u32 prev = 0xFFFFFFFFu;
            for (int i = 0; i < n; ++i) {
                uint2 r = rec2[start + i];
                if (r.x != prev) { rec2[start + uc].x = r.x; ++uc; prev = r.x; }
                __builtin_nontemporal_store((u32)(uc - 1), &idxmap[r.y]);
            }
            crossCnt[v] = (u32)uc;
        }
    }
}

// 4 buckets per 256-thread block (one per wave); lane i -> unique crossing
// edge i -> vertex crossScan[v]+i. Output writes are globally contiguous.
__global__ __launch_bounds__(256) void k_verts(
    const u32* crossCnt, const u32* bucketStart, const uint2* rec2, const u32* crossScan,
    const float* pos, const float* sdf, float* out, int V)
{
    int v = blockIdx.x * 4 + (threadIdx.x >> 6);
    if (v >= V) return;
    int lane = threadIdx.x & 63;
    int u = (int)crossCnt[v];
    if (u == 0) return;
    long long start = (long long)bucketStart[v];
    int cBase = (int)crossScan[v];
    float s0 = sdf[v];
    float p0x = pos[3 * v], p0y = pos[3 * v + 1], p0z = pos[3 * v + 2];
    for (int i = lane; i < u; i += 64) {
        int b = (int)rec2[start + i].x;
        long long k = cBase + i;
        float s1 = sdf[b];
        float d = s0 - s1;
        float w0 = -s1 / d, w1 = s0 / d;
        out[3 * k + 0] = p0x * w0 + pos[3 * b + 0] * w1;
        out[3 * k + 1] = p0y * w0 + pos[3 * b + 1] * w1;
        out[3 * k + 2] = p0z * w0 + pos[3 * b + 2] * w1;
    }
}

// faces + uv_idx. Edge->vertex id is a direct read: idx_map[6t+e] holds the
// local dedup index within bucket(a); global id = crossScan[a] + local.
__global__ void k_faces(const int* tet, const u8* ti8, const u64* tetScan,
                        const u32* idxmap, const u32* crossScan,
                        const u64* meta0, const u32* NePtr,
                        float* out, int T, int Ngrid, long long uvFloats)
{
    int t = blockIdx.x * 256 + threadIdx.x;
    if (t >= T) return;
    int ti = ti8[t];
    int nt = d_NUMTRI[ti];
    if (nt == 0) return;

    u64 tot = *meta0;
    int C1 = (int)((tot >> 21) & 0x1fffffull);
    int C2 = (int)(tot & 0x1fffffull);
    int Ne = (int)*NePtr;
    long long facesBase = 3LL * Ne;
    long long F = (long long)C1 + 2LL * C2;
    long long uvIdxBase = facesBase + 3LL * F + uvFloats;

    int4 q = reinterpret_cast<const int4*>(tet)[t];
    int idx[4] = {q.x, q.y, q.z, q.w};
    const uint2* imp = reinterpret_cast<const uint2*>(idxmap + 6ll * t);
    uint2 r0 = imp[0], r1 = imp[1], r2 = imp[2];
    u32 im[6] = {r0.x, r0.y, r1.x, r1.y, r2.x, r2.y};
    const int* row = d_TRI[ti];

    int emap[6];
    unsigned done = 0;
    float fv[6];
    #pragma unroll
    for (int j = 0; j < 6; ++j) {
        if (j >= 3 * nt) break;
        int e = row[j];
        if (!((done >> e) & 1)) {
            done |= 1u << e;
            int a = idx[d_E0[e]], b = idx[d_E1[e]];
            if (b < a) a = b;                  // a = min endpoint = bucket
            emap[e] = (int)crossScan[a] + (int)im[e];
        }
        fv[j] = (float)emap[e];
    }

    u64 sc = tetScan[t];
    int r1s = (int)((sc >> 21) & 0x1fffffull);
    int r2s = (int)(sc & 0x1fffffull);
    int tet_idx = (t / Ngrid) * Ngrid + (t % Ngrid);

    if (nt == 1) {
        long long f = r1s;
        out[facesBase + 3 * f + 0] = fv[0];
        out[facesBase + 3 * f + 1] = fv[1];
        out[facesBase + 3 * f + 2] = fv[2];
        out[uvIdxBase + 3 * f + 0] = (float)(4 * tet_idx);
        out[uvIdxBase + 3 * f + 1] = (float)(4 * tet_idx + 1);
        out[uvIdxBase + 3 * f + 2] = (float)(4 * tet_idx + 2);
    } else {
        long long f0 = (long long)C1 + 2LL * r2s;
        out[facesBase + 3 * f0 + 0] = fv[0];
        out[facesBase + 3 * f0 + 1] = fv[1];
        out[facesBase + 3 * f0 + 2] = fv[2];
        out[facesBase + 3 * (f0 + 1) + 0] = fv[3];
        out[facesBase + 3 * (f0 + 1) + 1] = fv[4];
        out[facesBase + 3 * (f0 + 1) + 2] = fv[5];
        out[uvIdxBase + 3 * f0 + 0] = (float)(4 * tet_idx);
        out[uvIdxBase + 3 * f0 + 1] = (float)(4 * tet_idx + 1);
        out[uvIdxBase + 3 * f0 + 2] = (float)(4 * tet_idx + 2);
        out[uvIdxBase + 3 * (f0 + 1) + 0] = (float)(4 * tet_idx);
        out[uvIdxBase + 3 * (f0 + 1) + 1] = (float)(4 * tet_idx + 2);
        out[uvIdxBase + 3 * (f0 + 1) + 2] = (float)(4 * tet_idx + 3);
    }
}

__global__ void k_uvs(float* out, const u64* meta0, const u32* NePtr, int Ngrid) {
    int c = blockIdx.x * 256 + threadIdx.x;
    int total = Ngrid * Ngrid;
    if (c >= total) return;
    u64 tot = *meta0;
    int C1 = (int)((tot >> 21) & 0x1fffffull);
    int C2 = (int)(tot & 0x1fffffull);
    int Ne = (int)*NePtr;
    long long uvBase = 3LL * Ne + 3LL * ((long long)C1 + 2LL * C2);
    int i = c / Ngrid, j = c % Ngrid;
    double step = (Ngrid > 1) ? (1.0 - 1.0 / (double)Ngrid) / (double)(Ngrid - 1) : 0.0;
    float x = (float)((double)j * step);
    float y = (float)((double)i * step);
    float pad = (float)(0.9 / (double)Ngrid);
    long long o = uvBase + 8LL * c;
    out[o + 0] = x;       out[o + 1] = y;
    out[o + 2] = x + pad; out[o + 3] = y;
    out[o + 4] = x + pad; out[o + 5] = y + pad;
    out[o + 6] = x;       out[o + 7] = y + pad;
}

// ---------------- host ----------------
template <typename T>
static void run_scan_t(const T* in, T* out, int n, T* blockSums, T* totalOut,
                       hipStream_t stream) {
    int nb = (n + SCAN_TILE - 1) / SCAN_TILE;
    scanA_t<T><<<nb, SCAN_BLOCK, 0, stream>>>(in, out, n, blockSums);
    scanB_t<T><<<1, 256, 0, stream>>>(blockSums, nb, totalOut);
    scanC_t<T><<<nb, SCAN_BLOCK, 0, stream>>>(out, n, blockSums);
}

extern "C" void kernel_launch(void* const* d_in, const int* in_sizes, int n_in,
                              void* d_out, int out_size, void* d_ws, size_t ws_size,
                              hipStream_t stream) {
    const float* pos = (const float*)d_in[0];
    const float* sdf = (const float*)d_in[1];
    const int* tet = (const int*)d_in[2];
    int V = in_sizes[1];
    int T = in_sizes[2] / 4;
    float* out = (float*)d_out;

    int NB = (V + BIN_VR - 1) / BIN_VR;
    int gB = (T + TETS_PER_BLOCK - 1) / TETS_PER_BLOCK;
    int nHist = NB * gB;

    char* p = (char*)d_ws;
    auto alloc = [&](size_t bytes) -> void* {
        void* r = (void*)p;
        p += (bytes + 255) & ~(size_t)255;
        return r;
    };
    u8*  ti8           = (u8*) alloc((size_t)T);
    u64* tetPack       = (u64*)alloc((size_t)T * 8);
    u64* tetScan       = (u64*)alloc((size_t)T * 8);
    u32* blockHist     = (u32*)alloc((size_t)nHist * 4);
    u32* blockHistScan = (u32*)alloc((size_t)nHist * 4);
    u32* binData       = (u32*)alloc((size_t)6 * T * 4);   // reused as idxmap
    u32* binProv       = (u32*)alloc((size_t)6 * T * 4);
    u32* bucketCnt     = (u32*)alloc((size_t)V * 4);
    u32* padCnt        = (u32*)alloc((size_t)V * 4);
    u32* bucketStart   = (u32*)alloc((size_t)V * 4);
    u32* crossCnt      = (u32*)alloc((size_t)V * 4);
    u32* crossScan     = (u32*)alloc((size_t)V * 4);
    uint2* rec2        = (uint2*)alloc(((size_t)6 * T + 4 * (size_t)V) * 8);
    u32* bigList       = (u32*)alloc((size_t)V * 4);
    u64* blockSums64   = (u64*)alloc(2048 * 8);
    u32* blockSums32   = (u32*)alloc(2048 * 4);
    u64* meta64        = (u64*)alloc(8 * 8);
    u32* NePtr         = (u32*)(meta64 + 4);
    u32* NeInstPtr     = (u32*)(meta64 + 5);
    u32* bigCnt        = (u32*)(meta64 + 6);

    // idx_map[t*6+e] aliases binData: binData's last reader is k_binscatter,
    // idxmap's first writer is k_sortdedup (strictly after). 6T u32 exactly.
    u32* idxmap = binData;

    long long M = (2LL * T + 1) / 2;
    int Ngrid = (int)std::sqrt((double)M);
    while ((long long)Ngrid * Ngrid < M) ++Ngrid;
    if (Ngrid < 1) Ngrid = 1;
    long long uvFloats = 8LL * Ngrid * Ngrid;

    int gT = (T + 255) / 256;
    int gV4 = (V + 3) / 4;

    k_classify_hist<<<gB, 256, 0, stream>>>(tet, sdf, ti8, tetPack, blockHist,
                                            bigCnt, T, NB, gB);
    run_scan_t<u64>(tetPack, tetScan, T, blockSums64, meta64, stream);
    run_scan_t<u32>(blockHist, blockHistScan, nHist, blockSums32, NeInstPtr, stream);
    k_binfill<<<gB, 256, 0, stream>>>(tet, ti8, blockHistScan, binData, binProv,
                                      T, NB, gB);
    k_bincount<<<NB, 256, 0, stream>>>(blockHistScan, NeInstPtr, binData,
                                       bucketCnt, padCnt, V, NB, gB);
    run_scan_t<u32>(padCnt, bucketStart, V, blockSums32, nullptr, stream);
    k_binscatter<<<NB, 256, 0, stream>>>(blockHistScan, NeInstPtr, binData,
                                         binProv, bucketStart, rec2, V, NB, gB);
    k_sortdedup<<<gV4, 256, 0, stream>>>(bucketCnt, bucketStart, rec2,
                                         idxmap, crossCnt, bigList, bigCnt, V);
    k_sortbig<<<128, 64, 0, stream>>>(bigList, bigCnt, bucketCnt, bucketStart,
                                      rec2, idxmap, crossCnt);
    run_scan_t<u32>(crossCnt, crossScan, V, blockSums32, NePtr, stream);
    k_verts<<<gV4, 256, 0, stream>>>(crossCnt, bucketStart, rec2, crossScan,
                                     pos, sdf, out, V);
    k_faces<<<gT, 256, 0, stream>>>(tet, ti8, tetScan, idxmap, crossScan,
                                    meta64, NePtr, out, T, Ngrid, uvFloats);
    int gUV = (Ngrid * Ngrid + 255) / 256;
    k_uvs<<<gUV, 256, 0, stream>>>(out, meta64, NePtr, Ngrid);
}